// Round 1
// baseline (189.383 us; speedup 1.0000x reference)
//
#include <hip/hip_runtime.h>

#define NB   16
#define CD   256
#define HWD  4096
#define BM   64
#define BL   64
#define LDP  264   // 256 + 8 bf16 pad: keeps ds_read_b128 16B-aligned, spreads banks

typedef __attribute__((ext_vector_type(8))) short short8;
typedef __attribute__((ext_vector_type(4))) float f32x4;

static __device__ __forceinline__ float b2f(unsigned short u) {
  union { unsigned int i; float f; } x; x.i = ((unsigned int)u) << 16; return x.f;
}
static __device__ __forceinline__ unsigned short f2b(float f) {
  union { float f; unsigned int i; } x; x.f = f;
  return (unsigned short)((x.i + 0x7fffu + ((x.i >> 16) & 1u)) >> 16);
}

// ---------------------------------------------------------------------------
// Kernel A: keys/queries/values = W @ x + b  (per image), bf16 out.
// Queries get the per-head (32-channel) softmax applied inline.
// Tile: 64 (out ch) x 64 (spatial), K=256 fully resident in LDS.
// ---------------------------------------------------------------------------
__global__ __launch_bounds__(256, 2)
void kqv_kernel(const float* __restrict__ x,
                const float* __restrict__ Wk, const float* __restrict__ bk,
                const float* __restrict__ Wq, const float* __restrict__ bq,
                const float* __restrict__ Wv, const float* __restrict__ bv,
                unsigned short* __restrict__ keys,
                unsigned short* __restrict__ qsm,
                unsigned short* __restrict__ vals)
{
  __shared__ __align__(16) unsigned short As[BM * LDP];
  __shared__ __align__(16) unsigned short Bs[BL * LDP];

  const int t  = threadIdx.x;
  const int lt = blockIdx.x;        // spatial tile 0..63
  const int mt = blockIdx.y;        // 0..11 (0-3 keys, 4-7 queries, 8-11 values)
  const int n  = blockIdx.z;
  const int l0 = lt * BL;
  const int wsel   = mt >> 2;
  const int ocbase = (mt & 3) * BM;

  const float* W    = (wsel == 0) ? Wk : (wsel == 1) ? Wq : Wv;
  const float* bias = (wsel == 0) ? bk : (wsel == 1) ? bq : bv;

  // --- load A tile: W rows [ocbase, ocbase+64) x 256, fp32 -> bf16 ---
#pragma unroll
  for (int i = 0; i < 16; ++i) {
    int idx = t + i * 256;          // 0..4095
    int row = idx >> 6;
    int cg  = (idx & 63) << 2;
    const f32x4 v = *(const f32x4*)(W + (size_t)(ocbase + row) * CD + cg);
    unsigned int lo = (unsigned int)f2b(v.x) | ((unsigned int)f2b(v.y) << 16);
    unsigned int hi = (unsigned int)f2b(v.z) | ((unsigned int)f2b(v.w) << 16);
    *(uint2*)(As + row * LDP + cg) = make_uint2(lo, hi);
  }
  // --- load B tile transposed: Bs[l][c] = x[n][c][l0+l] ---
  const float* xn = x + (size_t)n * CD * HWD;
  {
    int l  = t & 63;
    int g0 = t >> 6;
#pragma unroll
    for (int i = 0; i < 16; ++i) {
      int c = (g0 + i * 4) << 2;
      float v0 = xn[(size_t)(c + 0) * HWD + l0 + l];
      float v1 = xn[(size_t)(c + 1) * HWD + l0 + l];
      float v2 = xn[(size_t)(c + 2) * HWD + l0 + l];
      float v3 = xn[(size_t)(c + 3) * HWD + l0 + l];
      unsigned int lo = (unsigned int)f2b(v0) | ((unsigned int)f2b(v1) << 16);
      unsigned int hi = (unsigned int)f2b(v2) | ((unsigned int)f2b(v3) << 16);
      *(uint2*)(Bs + l * LDP + c) = make_uint2(lo, hi);
    }
  }
  __syncthreads();

  const int w = t >> 6, lane = t & 63;
  const int wr = (w >> 1) * 32, wc = (w & 1) * 32;
  const int lhi = lane >> 4, llo = lane & 15;

  f32x4 acc[2][2] = {};
#pragma unroll
  for (int kk = 0; kk < 8; ++kk) {
    const int koff = kk * 32 + lhi * 8;
    short8 a0 = *(const short8*)(As + (wr + llo) * LDP + koff);
    short8 a1 = *(const short8*)(As + (wr + 16 + llo) * LDP + koff);
    short8 b0 = *(const short8*)(Bs + (wc + llo) * LDP + koff);
    short8 b1 = *(const short8*)(Bs + (wc + 16 + llo) * LDP + koff);
    acc[0][0] = __builtin_amdgcn_mfma_f32_16x16x32_bf16(a0, b0, acc[0][0], 0, 0, 0);
    acc[0][1] = __builtin_amdgcn_mfma_f32_16x16x32_bf16(a0, b1, acc[0][1], 0, 0, 0);
    acc[1][0] = __builtin_amdgcn_mfma_f32_16x16x32_bf16(a1, b0, acc[1][0], 0, 0, 0);
    acc[1][1] = __builtin_amdgcn_mfma_f32_16x16x32_bf16(a1, b1, acc[1][1], 0, 0, 0);
  }
  __syncthreads();   // everyone done reading As before we overlay it

  // --- stage tile (+bias) in fp32 LDS (overlays As) ---
  float* Qs = (float*)As;           // 64 x 65
#pragma unroll
  for (int mi = 0; mi < 2; ++mi)
#pragma unroll
    for (int ni = 0; ni < 2; ++ni)
#pragma unroll
      for (int r = 0; r < 4; ++r) {
        int row = wr + mi * 16 + lhi * 4 + r;
        int col = wc + ni * 16 + llo;
        Qs[row * 65 + col] = acc[mi][ni][r] + bias[ocbase + row];
      }
  __syncthreads();

  if (wsel == 1) {                  // queries: softmax over 32-channel head groups
    if (t < 128) {
      int col = t & 63, g = t >> 6;
      float m = -1e30f;
#pragma unroll
      for (int i = 0; i < 32; ++i) m = fmaxf(m, Qs[(g * 32 + i) * 65 + col]);
      float s = 0.f;
#pragma unroll
      for (int i = 0; i < 32; ++i) {
        float e = __expf(Qs[(g * 32 + i) * 65 + col] - m);
        Qs[(g * 32 + i) * 65 + col] = e;
        s += e;
      }
      float inv = 1.f / s;
#pragma unroll
      for (int i = 0; i < 32; ++i) Qs[(g * 32 + i) * 65 + col] *= inv;
    }
    __syncthreads();
  }

  unsigned short* dst = (wsel == 0) ? keys : (wsel == 1) ? qsm : vals;
  {
    int l = t & 63, r0 = t >> 6;
#pragma unroll
    for (int i = 0; i < 16; ++i) {
      int row = r0 + i * 4;
      dst[(size_t)(n * CD + ocbase + row) * HWD + l0 + l] = f2b(Qs[row * 65 + l]);
    }
  }
}

// ---------------------------------------------------------------------------
// Kernel B: per key-row (n*256 rows) max and 1/sum(exp) over hw=4096
// ---------------------------------------------------------------------------
__global__ __launch_bounds__(256)
void rowstats_kernel(const unsigned short* __restrict__ keys,
                     float* __restrict__ stats)
{
  __shared__ float red[8];
  const int r = blockIdx.x;          // 0..4095
  const int t = threadIdx.x;
  const unsigned short* rowp = keys + (size_t)r * HWD;
  float v[16];
  float m = -1e30f;
#pragma unroll
  for (int i = 0; i < 2; ++i) {
    const short8 u = *(const short8*)(rowp + t * 8 + i * 2048);
#pragma unroll
    for (int j = 0; j < 8; ++j) {
      v[i * 8 + j] = b2f((unsigned short)u[j]);
      m = fmaxf(m, v[i * 8 + j]);
    }
  }
#pragma unroll
  for (int off = 1; off < 64; off <<= 1) m = fmaxf(m, __shfl_xor(m, off));
  if ((t & 63) == 0) red[t >> 6] = m;
  __syncthreads();
  m = fmaxf(fmaxf(red[0], red[1]), fmaxf(red[2], red[3]));
  float s = 0.f;
#pragma unroll
  for (int i = 0; i < 16; ++i) s += __expf(v[i] - m);
#pragma unroll
  for (int off = 1; off < 64; off <<= 1) s += __shfl_xor(s, off);
  if ((t & 63) == 0) red[4 + (t >> 6)] = s;
  __syncthreads();
  if (t == 0) {
    s = red[4] + red[5] + red[6] + red[7];
    stats[r * 2]     = m;
    stats[r * 2 + 1] = 1.f / s;
  }
}

// ---------------------------------------------------------------------------
// Kernel C: ctx[n,h] (32x32) = softmax_k(keys) @ vals^T, streamed from global.
// grid (2 halves, 128 nh); each block's 4 waves cover 512 l each.
// ---------------------------------------------------------------------------
__global__ __launch_bounds__(256)
void ctx_kernel(const unsigned short* __restrict__ keys,
                const unsigned short* __restrict__ vals,
                const float* __restrict__ stats,
                float* __restrict__ ctxp)       // [2][128][32][32]
{
  __shared__ float Cs[4][32][33];
  const int hf = blockIdx.x;          // 0,1
  const int nh = blockIdx.y;          // 0..127
  const int n = nh >> 3, h = nh & 7;
  const int t = threadIdx.x, w = t >> 6, lane = t & 63;
  const int lhi = lane >> 4, llo = lane & 15;
  const int lbase = hf * 2048 + w * 512;

  const unsigned short* kr = keys + (size_t)(n * CD + h * 32) * HWD;
  const unsigned short* vr = vals + (size_t)(n * CD + h * 32) * HWD;

  float mx[2], inv[2];
#pragma unroll
  for (int mi = 0; mi < 2; ++mi) {
    int kc = mi * 16 + llo;
    mx[mi]  = stats[(n * CD + h * 32 + kc) * 2];
    inv[mi] = stats[(n * CD + h * 32 + kc) * 2 + 1];
  }

  f32x4 acc[2][2] = {};
  for (int ks = 0; ks < 16; ++ks) {
    const int loff = lbase + ks * 32 + lhi * 8;
    short8 a[2], b[2];
#pragma unroll
    for (int mi = 0; mi < 2; ++mi) {
      const short8 u = *(const short8*)(kr + (size_t)(mi * 16 + llo) * HWD + loff);
      short8 af;
#pragma unroll
      for (int j = 0; j < 8; ++j)
        af[j] = (short)f2b(__expf(b2f((unsigned short)u[j]) - mx[mi]) * inv[mi]);
      a[mi] = af;
    }
#pragma unroll
    for (int ni = 0; ni < 2; ++ni)
      b[ni] = *(const short8*)(vr + (size_t)(ni * 16 + llo) * HWD + loff);
    acc[0][0] = __builtin_amdgcn_mfma_f32_16x16x32_bf16(a[0], b[0], acc[0][0], 0, 0, 0);
    acc[0][1] = __builtin_amdgcn_mfma_f32_16x16x32_bf16(a[0], b[1], acc[0][1], 0, 0, 0);
    acc[1][0] = __builtin_amdgcn_mfma_f32_16x16x32_bf16(a[1], b[0], acc[1][0], 0, 0, 0);
    acc[1][1] = __builtin_amdgcn_mfma_f32_16x16x32_bf16(a[1], b[1], acc[1][1], 0, 0, 0);
  }

#pragma unroll
  for (int mi = 0; mi < 2; ++mi)
#pragma unroll
    for (int ni = 0; ni < 2; ++ni)
#pragma unroll
      for (int r = 0; r < 4; ++r)
        Cs[w][mi * 16 + lhi * 4 + r][ni * 16 + llo] = acc[mi][ni][r];
  __syncthreads();
#pragma unroll
  for (int i = 0; i < 4; ++i) {
    int e = t + i * 256;              // 0..1023
    int kc = e >> 5, vc = e & 31;
    float sum = Cs[0][kc][vc] + Cs[1][kc][vc] + Cs[2][kc][vc] + Cs[3][kc][vc];
    ctxp[((size_t)hf * 128 + nh) * 1024 + e] = sum;
  }
}

// ---------------------------------------------------------------------------
// Kernel D: M_n[o][h*32+kc] = sum_vc Wr[o][h*32+vc] * ctx[n,h][kc][vc], bf16
// ---------------------------------------------------------------------------
__global__ __launch_bounds__(256)
void proj_kernel(const float* __restrict__ ctxp, const float* __restrict__ Wr,
                 unsigned short* __restrict__ M)
{
  __shared__ float cs[32][33];
  const int nh = blockIdx.x;
  const int n = nh >> 3, h = nh & 7;
  const int t = threadIdx.x;
#pragma unroll
  for (int i = 0; i < 4; ++i) {
    int e = t + i * 256;
    cs[e >> 5][e & 31] = ctxp[(size_t)nh * 1024 + e] + ctxp[((size_t)128 + nh) * 1024 + e];
  }
  __syncthreads();
  float wreg[32];
  const float* wp = Wr + (size_t)t * 256 + h * 32;
#pragma unroll
  for (int i = 0; i < 8; ++i) {
    f32x4 v = *(const f32x4*)(wp + i * 4);
    wreg[i * 4] = v.x; wreg[i * 4 + 1] = v.y; wreg[i * 4 + 2] = v.z; wreg[i * 4 + 3] = v.w;
  }
  unsigned short o16[32];
#pragma unroll
  for (int kc = 0; kc < 32; ++kc) {
    float s = 0.f;
#pragma unroll
    for (int vv = 0; vv < 32; ++vv) s += wreg[vv] * cs[kc][vv];
    o16[kc] = f2b(s);
  }
  unsigned short* mp = M + (size_t)(n * CD + t) * 256 + h * 32;
#pragma unroll
  for (int i = 0; i < 8; ++i) {
    unsigned int lo = (unsigned int)o16[i * 4]     | ((unsigned int)o16[i * 4 + 1] << 16);
    unsigned int hi = (unsigned int)o16[i * 4 + 2] | ((unsigned int)o16[i * 4 + 3] << 16);
    *(uint2*)(mp + i * 4) = make_uint2(lo, hi);
  }
}

// ---------------------------------------------------------------------------
// Kernel E: out = M_n @ q_sm + br + x   (fp32 out, residual)
// ---------------------------------------------------------------------------
__global__ __launch_bounds__(256, 2)
void out_kernel(const unsigned short* __restrict__ M,
                const unsigned short* __restrict__ qsm,
                const float* __restrict__ br,
                const float* __restrict__ x,
                float* __restrict__ out)
{
  __shared__ __align__(16) unsigned short As[BM * LDP];
  __shared__ __align__(16) unsigned short Bs[BL * LDP];
  const int t = threadIdx.x;
  const int lt = blockIdx.x, mt = blockIdx.y, n = blockIdx.z;
  const int l0 = lt * BL, m0 = mt * BM;

  const unsigned short* Mn = M + (size_t)n * CD * 256;
#pragma unroll
  for (int i = 0; i < 8; ++i) {
    int idx = t + i * 256;            // 0..2047
    int row = idx >> 5, s8 = (idx & 31) << 3;
    *(short8*)(As + row * LDP + s8) = *(const short8*)(Mn + (size_t)(m0 + row) * 256 + s8);
  }
  const unsigned short* qn = qsm + (size_t)n * CD * HWD;
  {
    int l = t & 63, g0 = t >> 6;
#pragma unroll
    for (int i = 0; i < 16; ++i) {
      int c = (g0 + i * 4) << 2;
      unsigned short q0 = qn[(size_t)(c + 0) * HWD + l0 + l];
      unsigned short q1 = qn[(size_t)(c + 1) * HWD + l0 + l];
      unsigned short q2 = qn[(size_t)(c + 2) * HWD + l0 + l];
      unsigned short q3 = qn[(size_t)(c + 3) * HWD + l0 + l];
      unsigned int lo = (unsigned int)q0 | ((unsigned int)q1 << 16);
      unsigned int hi = (unsigned int)q2 | ((unsigned int)q3 << 16);
      *(uint2*)(Bs + l * LDP + c) = make_uint2(lo, hi);
    }
  }
  __syncthreads();

  const int w = t >> 6, lane = t & 63;
  const int wr = (w >> 1) * 32, wc = (w & 1) * 32;
  const int lhi = lane >> 4, llo = lane & 15;

  f32x4 acc[2][2] = {};
#pragma unroll
  for (int kk = 0; kk < 8; ++kk) {
    const int koff = kk * 32 + lhi * 8;
    short8 a0 = *(const short8*)(As + (wr + llo) * LDP + koff);
    short8 a1 = *(const short8*)(As + (wr + 16 + llo) * LDP + koff);
    short8 b0 = *(const short8*)(Bs + (wc + llo) * LDP + koff);
    short8 b1 = *(const short8*)(Bs + (wc + 16 + llo) * LDP + koff);
    acc[0][0] = __builtin_amdgcn_mfma_f32_16x16x32_bf16(a0, b0, acc[0][0], 0, 0, 0);
    acc[0][1] = __builtin_amdgcn_mfma_f32_16x16x32_bf16(a0, b1, acc[0][1], 0, 0, 0);
    acc[1][0] = __builtin_amdgcn_mfma_f32_16x16x32_bf16(a1, b0, acc[1][0], 0, 0, 0);
    acc[1][1] = __builtin_amdgcn_mfma_f32_16x16x32_bf16(a1, b1, acc[1][1], 0, 0, 0);
  }
  __syncthreads();

  float* Qs = (float*)As;             // 64 x 65
#pragma unroll
  for (int mi = 0; mi < 2; ++mi)
#pragma unroll
    for (int ni = 0; ni < 2; ++ni)
#pragma unroll
      for (int r = 0; r < 4; ++r) {
        int row = wr + mi * 16 + lhi * 4 + r;
        int col = wc + ni * 16 + llo;
        Qs[row * 65 + col] = acc[mi][ni][r] + br[m0 + row];
      }
  __syncthreads();

  const float* xn = x + (size_t)n * CD * HWD;
  {
    int l = t & 63, r0 = t >> 6;
#pragma unroll
    for (int i = 0; i < 16; ++i) {
      int row = r0 + i * 4;
      size_t off = (size_t)(m0 + row) * HWD + l0 + l;
      out[(size_t)n * CD * HWD + off] = Qs[row * 65 + l] + xn[off];
    }
  }
}

// ---------------------------------------------------------------------------
extern "C" void kernel_launch(void* const* d_in, const int* in_sizes, int n_in,
                              void* d_out, int out_size, void* d_ws, size_t ws_size,
                              hipStream_t stream) {
  const float* x  = (const float*)d_in[0];
  const float* Wk = (const float*)d_in[1];
  const float* bk = (const float*)d_in[2];
  const float* Wq = (const float*)d_in[3];
  const float* bq = (const float*)d_in[4];
  const float* Wv = (const float*)d_in[5];
  const float* bv = (const float*)d_in[6];
  const float* Wr = (const float*)d_in[7];
  const float* br = (const float*)d_in[8];
  float* out = (float*)d_out;

  char* ws = (char*)d_ws;
  // ws layout (bytes): keys 32M | vals 32M | qsm 32M | stats 32K | ctx 1M | M 2M
  unsigned short* keys = (unsigned short*)(ws);
  unsigned short* vals = (unsigned short*)(ws + 33554432);
  unsigned short* qsm  = (unsigned short*)(ws + 67108864);
  float* stats         = (float*)(ws + 100663296);
  float* ctxp          = (float*)(ws + 100696064);
  unsigned short* M    = (unsigned short*)(ws + 101744640);

  hipLaunchKernelGGL(kqv_kernel, dim3(64, 12, NB), dim3(256), 0, stream,
                     x, Wk, bk, Wq, bq, Wv, bv, keys, qsm, vals);
  hipLaunchKernelGGL(rowstats_kernel, dim3(NB * CD), dim3(256), 0, stream, keys, stats);
  hipLaunchKernelGGL(ctx_kernel, dim3(2, 128), dim3(256), 0, stream,
                     keys, vals, stats, ctxp);
  hipLaunchKernelGGL(proj_kernel, dim3(128), dim3(256), 0, stream, ctxp, Wr, M);
  hipLaunchKernelGGL(out_kernel, dim3(64, 4, NB), dim3(256), 0, stream,
                     M, qsm, br, x, out);
}

// Round 2
// 134.834 us; speedup vs baseline: 1.4046x; 1.4046x over previous
//
#include <hip/hip_runtime.h>

#define NB   16
#define CD   256
#define HWD  4096

typedef __attribute__((ext_vector_type(8))) short short8;
typedef __attribute__((ext_vector_type(4))) float f32x4;

static __device__ __forceinline__ float b2f(unsigned short u) {
  union { unsigned int i; float f; } x; x.i = ((unsigned int)u) << 16; return x.f;
}
static __device__ __forceinline__ unsigned short f2b(float f) {
  union { float f; unsigned int i; } x; x.f = f;
  return (unsigned short)((x.i + 0x7fffu + ((x.i >> 16) & 1u)) >> 16);
}

static __device__ __forceinline__ void gload16(const void* g, const unsigned short* l) {
  __builtin_amdgcn_global_load_lds(
      (const __attribute__((address_space(1))) void*)g,
      (__attribute__((address_space(3))) void*)l, 16, 0, 0);
}

// ---------------------------------------------------------------------------
// prep: Wk|Wq|Wv (each 256x256 f32) -> Wc bf16 [768][256]
// ---------------------------------------------------------------------------
__global__ __launch_bounds__(256)
void prep_kernel(const float* __restrict__ Wk, const float* __restrict__ Wq,
                 const float* __restrict__ Wv, unsigned short* __restrict__ Wc)
{
  int e4 = blockIdx.x * 256 + threadIdx.x;   // 0..49151
  int base = e4 * 4;                          // 0..196604
  int w = base >> 16, off = base & 65535;
  const float* W = (w == 0) ? Wk : (w == 1) ? Wq : Wv;
  f32x4 v = *(const f32x4*)(W + off);
  unsigned int lo = (unsigned int)f2b(v.x) | ((unsigned int)f2b(v.y) << 16);
  unsigned int hi = (unsigned int)f2b(v.z) | ((unsigned int)f2b(v.w) << 16);
  *(uint2*)(Wc + base) = make_uint2(lo, hi);
}

// ---------------------------------------------------------------------------
// xT: x [n][256][4096] f32 -> xT [n][4096][256] bf16  (tile transpose)
// ---------------------------------------------------------------------------
__global__ __launch_bounds__(256)
void xt_kernel(const float* __restrict__ x, unsigned short* __restrict__ xT)
{
  __shared__ __align__(16) unsigned short T[64 * 72];
  const int t = threadIdx.x;
  const int l0 = blockIdx.x * 64, c0 = blockIdx.y * 64, n = blockIdx.z;
  const int l = t & 63, cs = t >> 6;
  const float* xn = x + (size_t)n * CD * HWD;
#pragma unroll
  for (int i = 0; i < 16; ++i) {
    int c = cs + i * 4;
    T[l * 72 + c] = f2b(xn[(size_t)(c0 + c) * HWD + l0 + l]);
  }
  __syncthreads();
  unsigned short* dst = xT + ((size_t)n * HWD + l0) * CD + c0;
#pragma unroll
  for (int i = 0; i < 2; ++i) {
    int e = t + i * 256;            // 0..511
    int lr = e >> 3, c8 = (e & 7) * 8;
    *(short8*)(dst + (size_t)lr * CD + c8) = *(const short8*)(T + lr * 72 + c8);
  }
}

// ---------------------------------------------------------------------------
// kqv: [keys;queries;values][768][4096] = Wc @ xT^T + bias, per image.
// 128x128 tile, BK=64, global_load_lds(16B) staging, 4 waves x 64x64.
// Queries get in-register head-group(32) softmax. bf16 outputs.
// ---------------------------------------------------------------------------
__global__ __launch_bounds__(256, 2)
void kqv_kernel(const unsigned short* __restrict__ Wc,
                const unsigned short* __restrict__ xT,
                const float* __restrict__ bk, const float* __restrict__ bq,
                const float* __restrict__ bv,
                unsigned short* __restrict__ keys,
                unsigned short* __restrict__ qsm,
                unsigned short* __restrict__ vals)
{
  __shared__ __align__(16) unsigned short smem[17408];  // As 8192 | Bs 8192; epilogue: 128x136
  unsigned short* As = smem;
  unsigned short* Bs = smem + 8192;

  const int t  = threadIdx.x;
  const int lt = blockIdx.x;        // spatial tile 0..31
  const int mt = blockIdx.y;        // 0..5
  const int n  = blockIdx.z;
  const int l0 = lt * 128;
  const int m0 = mt * 128;
  const int wsel = m0 >> 8;         // 0 keys, 1 queries, 2 values
  const int ocbase = m0 & 255;

  const unsigned short* Ag  = Wc;
  const unsigned short* Btn = xT + (size_t)n * HWD * CD;

  const int w = t >> 6, lane = t & 63;
  const int wr = (w >> 1) * 64, wc = (w & 1) * 64;
  const int lhi = lane >> 4, llo = lane & 15;

  f32x4 acc[4][4] = {};

  const int srow = t >> 3, sslot = (t & 7) * 8;   // staging: 8 lanes/row
  for (int ks = 0; ks < 4; ++ks) {
    const int k0 = ks * 64;
#pragma unroll
    for (int i = 0; i < 4; ++i) {
      int row = srow + i * 32;
      gload16(Ag + (size_t)(m0 + row) * CD + k0 + sslot, As + (t + i * 256) * 8);
      gload16(Btn + (size_t)(l0 + row) * CD + k0 + sslot, Bs + (t + i * 256) * 8);
    }
    __syncthreads();
#pragma unroll
    for (int kk = 0; kk < 2; ++kk) {
      const int koff = kk * 32 + lhi * 8;
      short8 a[4], b[4];
#pragma unroll
      for (int mi = 0; mi < 4; ++mi)
        a[mi] = *(const short8*)(As + (wr + mi * 16 + llo) * 64 + koff);
#pragma unroll
      for (int ni = 0; ni < 4; ++ni)
        b[ni] = *(const short8*)(Bs + (wc + ni * 16 + llo) * 64 + koff);
#pragma unroll
      for (int mi = 0; mi < 4; ++mi)
#pragma unroll
        for (int ni = 0; ni < 4; ++ni)
          acc[mi][ni] = __builtin_amdgcn_mfma_f32_16x16x32_bf16(a[mi], b[ni], acc[mi][ni], 0, 0, 0);
    }
    __syncthreads();
  }

  // --- bias ---
  const float* bias = (wsel == 0) ? bk : (wsel == 1) ? bq : bv;
  float breg[4][4];
#pragma unroll
  for (int mi = 0; mi < 4; ++mi)
#pragma unroll
    for (int r = 0; r < 4; ++r)
      breg[mi][r] = bias[ocbase + wr + mi * 16 + lhi * 4 + r];
#pragma unroll
  for (int mi = 0; mi < 4; ++mi)
#pragma unroll
    for (int ni = 0; ni < 4; ++ni)
#pragma unroll
      for (int r = 0; r < 4; ++r)
        acc[mi][ni][r] += breg[mi][r];

  // --- queries: softmax over 32-row head groups, fully in-register ---
  if (wsel == 1) {
#pragma unroll
    for (int g = 0; g < 2; ++g) {
#pragma unroll
      for (int ni = 0; ni < 4; ++ni) {
        float m = -1e30f;
#pragma unroll
        for (int mi = 2 * g; mi < 2 * g + 2; ++mi)
#pragma unroll
          for (int r = 0; r < 4; ++r) m = fmaxf(m, acc[mi][ni][r]);
        m = fmaxf(m, __shfl_xor(m, 16));
        m = fmaxf(m, __shfl_xor(m, 32));
        float s = 0.f;
#pragma unroll
        for (int mi = 2 * g; mi < 2 * g + 2; ++mi)
#pragma unroll
          for (int r = 0; r < 4; ++r) {
            float e = __expf(acc[mi][ni][r] - m);
            acc[mi][ni][r] = e;
            s += e;
          }
        s += __shfl_xor(s, 16);
        s += __shfl_xor(s, 32);
        float inv = 1.f / s;
#pragma unroll
        for (int mi = 2 * g; mi < 2 * g + 2; ++mi)
#pragma unroll
          for (int r = 0; r < 4; ++r) acc[mi][ni][r] *= inv;
      }
    }
  }

  // --- stage bf16 tile in LDS (128 x 136), then coalesced store ---
  unsigned short* Co = smem;
#pragma unroll
  for (int mi = 0; mi < 4; ++mi)
#pragma unroll
    for (int ni = 0; ni < 4; ++ni) {
      int col = wc + ni * 16 + llo;
#pragma unroll
      for (int r = 0; r < 4; ++r) {
        int row = wr + mi * 16 + lhi * 4 + r;
        Co[row * 136 + col] = f2b(acc[mi][ni][r]);
      }
    }
  __syncthreads();

  unsigned short* dst = ((wsel == 0) ? keys : (wsel == 1) ? qsm : vals)
                        + ((size_t)(n * CD + ocbase)) * HWD + l0;
#pragma unroll
  for (int i = 0; i < 8; ++i) {
    int e = t + i * 256;            // 0..2047
    int row = e >> 4, c8 = (e & 15) * 8;
    *(short8*)(dst + (size_t)row * HWD + c8) = *(const short8*)(Co + row * 136 + c8);
  }
}

// ---------------------------------------------------------------------------
// rowstats: per key-row max and 1/sum(exp) over hw=4096
// ---------------------------------------------------------------------------
__global__ __launch_bounds__(256)
void rowstats_kernel(const unsigned short* __restrict__ keys,
                     float* __restrict__ stats)
{
  __shared__ float red[8];
  const int r = blockIdx.x;          // 0..4095
  const int t = threadIdx.x;
  const unsigned short* rowp = keys + (size_t)r * HWD;
  float v[16];
  float m = -1e30f;
#pragma unroll
  for (int i = 0; i < 2; ++i) {
    const short8 u = *(const short8*)(rowp + t * 8 + i * 2048);
#pragma unroll
    for (int j = 0; j < 8; ++j) {
      v[i * 8 + j] = b2f((unsigned short)u[j]);
      m = fmaxf(m, v[i * 8 + j]);
    }
  }
#pragma unroll
  for (int off = 1; off < 64; off <<= 1) m = fmaxf(m, __shfl_xor(m, off));
  if ((t & 63) == 0) red[t >> 6] = m;
  __syncthreads();
  m = fmaxf(fmaxf(red[0], red[1]), fmaxf(red[2], red[3]));
  float s = 0.f;
#pragma unroll
  for (int i = 0; i < 16; ++i) s += __expf(v[i] - m);
#pragma unroll
  for (int off = 1; off < 64; off <<= 1) s += __shfl_xor(s, off);
  if ((t & 63) == 0) red[4 + (t >> 6)] = s;
  __syncthreads();
  if (t == 0) {
    s = red[4] + red[5] + red[6] + red[7];
    stats[r * 2]     = m;
    stats[r * 2 + 1] = 1.f / s;
  }
}

// ---------------------------------------------------------------------------
// ctx[n,h] (32x32) = softmax_k(keys) @ vals^T, streamed from global.
// ---------------------------------------------------------------------------
__global__ __launch_bounds__(256)
void ctx_kernel(const unsigned short* __restrict__ keys,
                const unsigned short* __restrict__ vals,
                const float* __restrict__ stats,
                float* __restrict__ ctxp)       // [2][128][32][32]
{
  __shared__ float Cs[4][32][33];
  const int hf = blockIdx.x;          // 0,1
  const int nh = blockIdx.y;          // 0..127
  const int n = nh >> 3, h = nh & 7;
  const int t = threadIdx.x, w = t >> 6, lane = t & 63;
  const int lhi = lane >> 4, llo = lane & 15;
  const int lbase = hf * 2048 + w * 512;

  const unsigned short* kr = keys + (size_t)(n * CD + h * 32) * HWD;
  const unsigned short* vr = vals + (size_t)(n * CD + h * 32) * HWD;

  float mx[2], inv[2];
#pragma unroll
  for (int mi = 0; mi < 2; ++mi) {
    int kc = mi * 16 + llo;
    mx[mi]  = stats[(n * CD + h * 32 + kc) * 2];
    inv[mi] = stats[(n * CD + h * 32 + kc) * 2 + 1];
  }

  f32x4 acc[2][2] = {};
  for (int ks = 0; ks < 16; ++ks) {
    const int loff = lbase + ks * 32 + lhi * 8;
    short8 a[2], b[2];
#pragma unroll
    for (int mi = 0; mi < 2; ++mi) {
      const short8 u = *(const short8*)(kr + (size_t)(mi * 16 + llo) * HWD + loff);
      short8 af;
#pragma unroll
      for (int j = 0; j < 8; ++j)
        af[j] = (short)f2b(__expf(b2f((unsigned short)u[j]) - mx[mi]) * inv[mi]);
      a[mi] = af;
    }
#pragma unroll
    for (int ni = 0; ni < 2; ++ni)
      b[ni] = *(const short8*)(vr + (size_t)(ni * 16 + llo) * HWD + loff);
    acc[0][0] = __builtin_amdgcn_mfma_f32_16x16x32_bf16(a[0], b[0], acc[0][0], 0, 0, 0);
    acc[0][1] = __builtin_amdgcn_mfma_f32_16x16x32_bf16(a[0], b[1], acc[0][1], 0, 0, 0);
    acc[1][0] = __builtin_amdgcn_mfma_f32_16x16x32_bf16(a[1], b[0], acc[1][0], 0, 0, 0);
    acc[1][1] = __builtin_amdgcn_mfma_f32_16x16x32_bf16(a[1], b[1], acc[1][1], 0, 0, 0);
  }

#pragma unroll
  for (int mi = 0; mi < 2; ++mi)
#pragma unroll
    for (int ni = 0; ni < 2; ++ni)
#pragma unroll
      for (int r = 0; r < 4; ++r)
        Cs[w][mi * 16 + lhi * 4 + r][ni * 16 + llo] = acc[mi][ni][r];
  __syncthreads();
#pragma unroll
  for (int i = 0; i < 4; ++i) {
    int e = t + i * 256;              // 0..1023
    int kc = e >> 5, vc = e & 31;
    float sum = Cs[0][kc][vc] + Cs[1][kc][vc] + Cs[2][kc][vc] + Cs[3][kc][vc];
    ctxp[((size_t)hf * 128 + nh) * 1024 + e] = sum;
  }
}

// ---------------------------------------------------------------------------
// proj: M_n[o][h*32+kc] = sum_vc Wr[o][h*32+vc] * ctx[n,h][kc][vc], bf16
// ---------------------------------------------------------------------------
__global__ __launch_bounds__(256)
void proj_kernel(const float* __restrict__ ctxp, const float* __restrict__ Wr,
                 unsigned short* __restrict__ M)
{
  __shared__ float cs[32][33];
  const int nh = blockIdx.x;
  const int n = nh >> 3, h = nh & 7;
  const int t = threadIdx.x;
#pragma unroll
  for (int i = 0; i < 4; ++i) {
    int e = t + i * 256;
    cs[e >> 5][e & 31] = ctxp[(size_t)nh * 1024 + e] + ctxp[((size_t)128 + nh) * 1024 + e];
  }
  __syncthreads();
  float wreg[32];
  const float* wp = Wr + (size_t)t * 256 + h * 32;
#pragma unroll
  for (int i = 0; i < 8; ++i) {
    f32x4 v = *(const f32x4*)(wp + i * 4);
    wreg[i * 4] = v.x; wreg[i * 4 + 1] = v.y; wreg[i * 4 + 2] = v.z; wreg[i * 4 + 3] = v.w;
  }
  unsigned short o16[32];
#pragma unroll
  for (int kc = 0; kc < 32; ++kc) {
    float s = 0.f;
#pragma unroll
    for (int vv = 0; vv < 32; ++vv) s += wreg[vv] * cs[kc][vv];
    o16[kc] = f2b(s);
  }
  unsigned short* mp = M + (size_t)(n * CD + t) * 256 + h * 32;
#pragma unroll
  for (int i = 0; i < 8; ++i) {
    unsigned int lo = (unsigned int)o16[i * 4]     | ((unsigned int)o16[i * 4 + 1] << 16);
    unsigned int hi = (unsigned int)o16[i * 4 + 2] | ((unsigned int)o16[i * 4 + 3] << 16);
    *(uint2*)(mp + i * 4) = make_uint2(lo, hi);
  }
}

// ---------------------------------------------------------------------------
// out = M_n @ q_sm + br + x   (fp32 out, residual)
// ---------------------------------------------------------------------------
__global__ __launch_bounds__(256, 2)
void out_kernel(const unsigned short* __restrict__ M,
                const unsigned short* __restrict__ qsm,
                const float* __restrict__ br,
                const float* __restrict__ x,
                float* __restrict__ out)
{
  __shared__ __align__(16) unsigned short As[64 * 264];
  __shared__ __align__(16) unsigned short Bs[64 * 264];
  const int t = threadIdx.x;
  const int lt = blockIdx.x, mt = blockIdx.y, n = blockIdx.z;
  const int l0 = lt * 64, m0 = mt * 64;

  const unsigned short* Mn = M + (size_t)n * CD * 256;
#pragma unroll
  for (int i = 0; i < 8; ++i) {
    int idx = t + i * 256;            // 0..2047
    int row = idx >> 5, s8 = (idx & 31) << 3;
    *(short8*)(As + row * 264 + s8) = *(const short8*)(Mn + (size_t)(m0 + row) * 256 + s8);
  }
  const unsigned short* qn = qsm + (size_t)n * CD * HWD;
  {
    int l = t & 63, g0 = t >> 6;
#pragma unroll
    for (int i = 0; i < 16; ++i) {
      int c = (g0 + i * 4) << 2;
      unsigned short q0 = qn[(size_t)(c + 0) * HWD + l0 + l];
      unsigned short q1 = qn[(size_t)(c + 1) * HWD + l0 + l];
      unsigned short q2 = qn[(size_t)(c + 2) * HWD + l0 + l];
      unsigned short q3 = qn[(size_t)(c + 3) * HWD + l0 + l];
      unsigned int lo = (unsigned int)q0 | ((unsigned int)q1 << 16);
      unsigned int hi = (unsigned int)q2 | ((unsigned int)q3 << 16);
      *(uint2*)(Bs + l * 264 + c) = make_uint2(lo, hi);
    }
  }
  __syncthreads();

  const int w = t >> 6, lane = t & 63;
  const int wr = (w >> 1) * 32, wc = (w & 1) * 32;
  const int lhi = lane >> 4, llo = lane & 15;

  f32x4 acc[2][2] = {};
#pragma unroll
  for (int kk = 0; kk < 8; ++kk) {
    const int koff = kk * 32 + lhi * 8;
    short8 a0 = *(const short8*)(As + (wr + llo) * 264 + koff);
    short8 a1 = *(const short8*)(As + (wr + 16 + llo) * 264 + koff);
    short8 b0 = *(const short8*)(Bs + (wc + llo) * 264 + koff);
    short8 b1 = *(const short8*)(Bs + (wc + 16 + llo) * 264 + koff);
    acc[0][0] = __builtin_amdgcn_mfma_f32_16x16x32_bf16(a0, b0, acc[0][0], 0, 0, 0);
    acc[0][1] = __builtin_amdgcn_mfma_f32_16x16x32_bf16(a0, b1, acc[0][1], 0, 0, 0);
    acc[1][0] = __builtin_amdgcn_mfma_f32_16x16x32_bf16(a1, b0, acc[1][0], 0, 0, 0);
    acc[1][1] = __builtin_amdgcn_mfma_f32_16x16x32_bf16(a1, b1, acc[1][1], 0, 0, 0);
  }
  __syncthreads();

  float* Qs = (float*)As;             // 64 x 65
#pragma unroll
  for (int mi = 0; mi < 2; ++mi)
#pragma unroll
    for (int ni = 0; ni < 2; ++ni)
#pragma unroll
      for (int r = 0; r < 4; ++r) {
        int row = wr + mi * 16 + lhi * 4 + r;
        int col = wc + ni * 16 + llo;
        Qs[row * 65 + col] = acc[mi][ni][r] + br[m0 + row];
      }
  __syncthreads();

  const float* xn = x + (size_t)n * CD * HWD;
  {
    int l = t & 63, r0 = t >> 6;
#pragma unroll
    for (int i = 0; i < 16; ++i) {
      int row = r0 + i * 4;
      size_t off = (size_t)(m0 + row) * HWD + l0 + l;
      out[(size_t)n * CD * HWD + off] = Qs[row * 65 + l] + xn[off];
    }
  }
}

// ---------------------------------------------------------------------------
extern "C" void kernel_launch(void* const* d_in, const int* in_sizes, int n_in,
                              void* d_out, int out_size, void* d_ws, size_t ws_size,
                              hipStream_t stream) {
  const float* x  = (const float*)d_in[0];
  const float* Wk = (const float*)d_in[1];
  const float* bk = (const float*)d_in[2];
  const float* Wq = (const float*)d_in[3];
  const float* bq = (const float*)d_in[4];
  const float* Wv = (const float*)d_in[5];
  const float* bv = (const float*)d_in[6];
  const float* Wr = (const float*)d_in[7];
  const float* br = (const float*)d_in[8];
  float* out = (float*)d_out;

  char* ws = (char*)d_ws;
  // ws layout (bytes): keys 32M | vals 32M | qsm 32M | stats 32K | ctx 1M | M 2M | Wc 384K
  unsigned short* keys = (unsigned short*)(ws);
  unsigned short* vals = (unsigned short*)(ws + 33554432);
  unsigned short* qsm  = (unsigned short*)(ws + 67108864);
  float* stats         = (float*)(ws + 100663296);
  float* ctxp          = (float*)(ws + 100696064);
  unsigned short* M    = (unsigned short*)(ws + 101744640);
  unsigned short* Wc   = (unsigned short*)(ws + 103841792);
  // xT (bf16, 32MB) lives in d_out scratch: fully dead before out_kernel writes it.
  unsigned short* xT   = (unsigned short*)d_out;

  hipLaunchKernelGGL(prep_kernel, dim3(192), dim3(256), 0, stream, Wk, Wq, Wv, Wc);
  hipLaunchKernelGGL(xt_kernel, dim3(64, 4, NB), dim3(256), 0, stream, x, xT);
  hipLaunchKernelGGL(kqv_kernel, dim3(32, 6, NB), dim3(256), 0, stream,
                     Wc, xT, bk, bq, bv, keys, qsm, vals);
  hipLaunchKernelGGL(rowstats_kernel, dim3(NB * CD), dim3(256), 0, stream, keys, stats);
  hipLaunchKernelGGL(ctx_kernel, dim3(2, 128), dim3(256), 0, stream,
                     keys, vals, stats, ctxp);
  hipLaunchKernelGGL(proj_kernel, dim3(128), dim3(256), 0, stream, ctxp, Wr, M);
  hipLaunchKernelGGL(out_kernel, dim3(64, 4, NB), dim3(256), 0, stream,
                     M, qsm, br, x, out);
}

// Round 3
// 130.932 us; speedup vs baseline: 1.4464x; 1.0298x over previous
//
#include <hip/hip_runtime.h>

#define NB   16
#define CD   256
#define HWD  4096

typedef __attribute__((ext_vector_type(8))) short short8;
typedef __attribute__((ext_vector_type(4))) float f32x4;

static __device__ __forceinline__ float b2f(unsigned short u) {
  union { unsigned int i; float f; } x; x.i = ((unsigned int)u) << 16; return x.f;
}
static __device__ __forceinline__ unsigned short f2b(float f) {
  union { float f; unsigned int i; } x; x.f = f;
  return (unsigned short)((x.i + 0x7fffu + ((x.i >> 16) & 1u)) >> 16);
}

static __device__ __forceinline__ void gload16(const void* g, const unsigned short* l) {
  __builtin_amdgcn_global_load_lds(
      (const __attribute__((address_space(1))) void*)g,
      (__attribute__((address_space(3))) void*)l, 16, 0, 0);
}

// ---------------------------------------------------------------------------
// prep: Wk|Wq|Wv (each 256x256 f32) -> Wc bf16 [768][256]
// ---------------------------------------------------------------------------
__global__ __launch_bounds__(256)
void prep_kernel(const float* __restrict__ Wk, const float* __restrict__ Wq,
                 const float* __restrict__ Wv, unsigned short* __restrict__ Wc)
{
  int e4 = blockIdx.x * 256 + threadIdx.x;   // 0..49151
  int base = e4 * 4;                          // 0..196604
  int w = base >> 16, off = base & 65535;
  const float* W = (w == 0) ? Wk : (w == 1) ? Wq : Wv;
  f32x4 v = *(const f32x4*)(W + off);
  unsigned int lo = (unsigned int)f2b(v.x) | ((unsigned int)f2b(v.y) << 16);
  unsigned int hi = (unsigned int)f2b(v.z) | ((unsigned int)f2b(v.w) << 16);
  *(uint2*)(Wc + base) = make_uint2(lo, hi);
}

// ---------------------------------------------------------------------------
// xT: x [n][256][4096] f32 -> xT [n][4096][256] bf16  (tile transpose)
// ---------------------------------------------------------------------------
__global__ __launch_bounds__(256)
void xt_kernel(const float* __restrict__ x, unsigned short* __restrict__ xT)
{
  __shared__ __align__(16) unsigned short T[64 * 72];
  const int t = threadIdx.x;
  const int l0 = blockIdx.x * 64, c0 = blockIdx.y * 64, n = blockIdx.z;
  const int l = t & 63, cs = t >> 6;
  const float* xn = x + (size_t)n * CD * HWD;
#pragma unroll
  for (int i = 0; i < 16; ++i) {
    int c = cs + i * 4;
    T[l * 72 + c] = f2b(xn[(size_t)(c0 + c) * HWD + l0 + l]);
  }
  __syncthreads();
  unsigned short* dst = xT + ((size_t)n * HWD + l0) * CD + c0;
#pragma unroll
  for (int i = 0; i < 2; ++i) {
    int e = t + i * 256;            // 0..511
    int lr = e >> 3, c8 = (e & 7) * 8;
    *(short8*)(dst + (size_t)lr * CD + c8) = *(const short8*)(T + lr * 72 + c8);
  }
}

// ---------------------------------------------------------------------------
// kqv: [keys;queries;values][768][4096] = Wc @ xT^T + bias, per image.
// 128x128 tile, BK=64 double-buffered, global_load_lds(16B) staging with
// pre-swizzled global source (st-style XOR on 16B slots), swizzled ds_read.
// Queries get in-register head-group(32) softmax. bf16 outputs.
// ---------------------------------------------------------------------------
__global__ __launch_bounds__(256, 2)
void kqv_kernel(const unsigned short* __restrict__ Wc,
                const unsigned short* __restrict__ xT,
                const float* __restrict__ bk, const float* __restrict__ bq,
                const float* __restrict__ bv,
                unsigned short* __restrict__ keys,
                unsigned short* __restrict__ qsm,
                unsigned short* __restrict__ vals)
{
  // 2 buffers x (As 128x64 + Bs 128x64) bf16 = 2 x 32KB.
  // Epilogue reuses first 34816B as Co[128][136].
  __shared__ __align__(16) unsigned short smem[32768];

  const int t  = threadIdx.x;
  const int lt = blockIdx.x;        // spatial tile 0..31
  const int mt = blockIdx.y;        // 0..5
  const int n  = blockIdx.z;
  const int l0 = lt * 128;
  const int m0 = mt * 128;
  const int wsel = m0 >> 8;         // 0 keys, 1 queries, 2 values
  const int ocbase = m0 & 255;

  const unsigned short* Ag  = Wc;
  const unsigned short* Btn = xT + (size_t)n * HWD * CD;

  const int w = t >> 6, lane = t & 63;
  const int wr = (w >> 1) * 64, wc = (w & 1) * 64;
  const int lhi = lane >> 4, llo = lane & 15;
  const int rsw = llo & 7;          // read-side XOR key (row&7 == llo&7 here)

  f32x4 acc[4][4] = {};

  // stage K-tile ks into buffer buf. LDS dest is LINEAR (gload_lds constraint);
  // the 16B-slot permutation is applied to the GLOBAL source address instead.
  auto stage = [&](int buf, int ks) {
    unsigned short* As = smem + buf * 16384;
    unsigned short* Bs = As + 8192;
    const int k0 = ks * 64;
#pragma unroll
    for (int i = 0; i < 4; ++i) {
      int s   = t + i * 256;        // 16B slot index 0..1023
      int row = s >> 3;             // 0..127
      int src = ((s ^ row) & 7) << 3;  // (slot ^ (row&7)) * 8 elements
      gload16(Ag  + (size_t)(m0 + row) * CD + k0 + src, As + s * 8);
      gload16(Btn + (size_t)(l0 + row) * CD + k0 + src, Bs + s * 8);
    }
  };

  auto compute = [&](int buf) {
    const unsigned short* As = smem + buf * 16384;
    const unsigned short* Bs = As + 8192;
#pragma unroll
    for (int kk = 0; kk < 2; ++kk) {
      const int slot = (kk * 4 + lhi) ^ rsw;
      short8 a[4], b[4];
#pragma unroll
      for (int mi = 0; mi < 4; ++mi)
        a[mi] = *(const short8*)(As + (wr + mi * 16 + llo) * 64 + slot * 8);
#pragma unroll
      for (int ni = 0; ni < 4; ++ni)
        b[ni] = *(const short8*)(Bs + (wc + ni * 16 + llo) * 64 + slot * 8);
#pragma unroll
      for (int mi = 0; mi < 4; ++mi)
#pragma unroll
        for (int ni = 0; ni < 4; ++ni)
          acc[mi][ni] = __builtin_amdgcn_mfma_f32_16x16x32_bf16(a[mi], b[ni], acc[mi][ni], 0, 0, 0);
    }
  };

  stage(0, 0);
  __syncthreads();                  // drains vmcnt(0): buf0 ready
#pragma unroll
  for (int ks = 0; ks < 4; ++ks) {
    if (ks < 3) stage((ks + 1) & 1, ks + 1);  // issue next-tile loads FIRST
    compute(ks & 1);                           // MFMA hides the load latency
    __syncthreads();                           // drain + handoff
  }

  // --- bias ---
  const float* bias = (wsel == 0) ? bk : (wsel == 1) ? bq : bv;
  float breg[4][4];
#pragma unroll
  for (int mi = 0; mi < 4; ++mi)
#pragma unroll
    for (int r = 0; r < 4; ++r)
      breg[mi][r] = bias[ocbase + wr + mi * 16 + lhi * 4 + r];
#pragma unroll
  for (int mi = 0; mi < 4; ++mi)
#pragma unroll
    for (int ni = 0; ni < 4; ++ni)
#pragma unroll
      for (int r = 0; r < 4; ++r)
        acc[mi][ni][r] += breg[mi][r];

  // --- queries: softmax over 32-row head groups, fully in-register ---
  if (wsel == 1) {
#pragma unroll
    for (int g = 0; g < 2; ++g) {
#pragma unroll
      for (int ni = 0; ni < 4; ++ni) {
        float m = -1e30f;
#pragma unroll
        for (int mi = 2 * g; mi < 2 * g + 2; ++mi)
#pragma unroll
          for (int r = 0; r < 4; ++r) m = fmaxf(m, acc[mi][ni][r]);
        m = fmaxf(m, __shfl_xor(m, 16));
        m = fmaxf(m, __shfl_xor(m, 32));
        float s = 0.f;
#pragma unroll
        for (int mi = 2 * g; mi < 2 * g + 2; ++mi)
#pragma unroll
          for (int r = 0; r < 4; ++r) {
            float e = __expf(acc[mi][ni][r] - m);
            acc[mi][ni][r] = e;
            s += e;
          }
        s += __shfl_xor(s, 16);
        s += __shfl_xor(s, 32);
        float inv = 1.f / s;
#pragma unroll
        for (int mi = 2 * g; mi < 2 * g + 2; ++mi)
#pragma unroll
          for (int r = 0; r < 4; ++r) acc[mi][ni][r] *= inv;
      }
    }
  }

  // --- stage bf16 tile in LDS (128 x 136), then coalesced store ---
  unsigned short* Co = smem;
#pragma unroll
  for (int mi = 0; mi < 4; ++mi)
#pragma unroll
    for (int ni = 0; ni < 4; ++ni) {
      int col = wc + ni * 16 + llo;
#pragma unroll
      for (int r = 0; r < 4; ++r) {
        int row = wr + mi * 16 + lhi * 4 + r;
        Co[row * 136 + col] = f2b(acc[mi][ni][r]);
      }
    }
  __syncthreads();

  unsigned short* dst = ((wsel == 0) ? keys : (wsel == 1) ? qsm : vals)
                        + ((size_t)(n * CD + ocbase)) * HWD + l0;
#pragma unroll
  for (int i = 0; i < 8; ++i) {
    int e = t + i * 256;            // 0..2047
    int row = e >> 4, c8 = (e & 15) * 8;
    *(short8*)(dst + (size_t)row * HWD + c8) = *(const short8*)(Co + row * 136 + c8);
  }
}

// ---------------------------------------------------------------------------
// rowstats: per key-row max and 1/sum(exp) over hw=4096
// ---------------------------------------------------------------------------
__global__ __launch_bounds__(256)
void rowstats_kernel(const unsigned short* __restrict__ keys,
                     float* __restrict__ stats)
{
  __shared__ float red[8];
  const int r = blockIdx.x;          // 0..4095
  const int t = threadIdx.x;
  const unsigned short* rowp = keys + (size_t)r * HWD;
  float v[16];
  float m = -1e30f;
#pragma unroll
  for (int i = 0; i < 2; ++i) {
    const short8 u = *(const short8*)(rowp + t * 8 + i * 2048);
#pragma unroll
    for (int j = 0; j < 8; ++j) {
      v[i * 8 + j] = b2f((unsigned short)u[j]);
      m = fmaxf(m, v[i * 8 + j]);
    }
  }
#pragma unroll
  for (int off = 1; off < 64; off <<= 1) m = fmaxf(m, __shfl_xor(m, off));
  if ((t & 63) == 0) red[t >> 6] = m;
  __syncthreads();
  m = fmaxf(fmaxf(red[0], red[1]), fmaxf(red[2], red[3]));
  float s = 0.f;
#pragma unroll
  for (int i = 0; i < 16; ++i) s += __expf(v[i] - m);
#pragma unroll
  for (int off = 1; off < 64; off <<= 1) s += __shfl_xor(s, off);
  if ((t & 63) == 0) red[4 + (t >> 6)] = s;
  __syncthreads();
  if (t == 0) {
    s = red[4] + red[5] + red[6] + red[7];
    stats[r * 2]     = m;
    stats[r * 2 + 1] = 1.f / s;
  }
}

// ---------------------------------------------------------------------------
// ctx[n,h] (32x32) = softmax_k(keys) @ vals^T, streamed from global.
// ---------------------------------------------------------------------------
__global__ __launch_bounds__(256)
void ctx_kernel(const unsigned short* __restrict__ keys,
                const unsigned short* __restrict__ vals,
                const float* __restrict__ stats,
                float* __restrict__ ctxp)       // [2][128][32][32]
{
  __shared__ float Cs[4][32][33];
  const int hf = blockIdx.x;          // 0,1
  const int nh = blockIdx.y;          // 0..127
  const int n = nh >> 3, h = nh & 7;
  const int t = threadIdx.x, w = t >> 6, lane = t & 63;
  const int lhi = lane >> 4, llo = lane & 15;
  const int lbase = hf * 2048 + w * 512;

  const unsigned short* kr = keys + (size_t)(n * CD + h * 32) * HWD;
  const unsigned short* vr = vals + (size_t)(n * CD + h * 32) * HWD;

  float mx[2], inv[2];
#pragma unroll
  for (int mi = 0; mi < 2; ++mi) {
    int kc = mi * 16 + llo;
    mx[mi]  = stats[(n * CD + h * 32 + kc) * 2];
    inv[mi] = stats[(n * CD + h * 32 + kc) * 2 + 1];
  }

  f32x4 acc[2][2] = {};
  for (int ks = 0; ks < 16; ++ks) {
    const int loff = lbase + ks * 32 + lhi * 8;
    short8 a[2], b[2];
#pragma unroll
    for (int mi = 0; mi < 2; ++mi) {
      const short8 u = *(const short8*)(kr + (size_t)(mi * 16 + llo) * HWD + loff);
      short8 af;
#pragma unroll
      for (int j = 0; j < 8; ++j)
        af[j] = (short)f2b(__expf(b2f((unsigned short)u[j]) - mx[mi]) * inv[mi]);
      a[mi] = af;
    }
#pragma unroll
    for (int ni = 0; ni < 2; ++ni)
      b[ni] = *(const short8*)(vr + (size_t)(ni * 16 + llo) * HWD + loff);
    acc[0][0] = __builtin_amdgcn_mfma_f32_16x16x32_bf16(a[0], b[0], acc[0][0], 0, 0, 0);
    acc[0][1] = __builtin_amdgcn_mfma_f32_16x16x32_bf16(a[0], b[1], acc[0][1], 0, 0, 0);
    acc[1][0] = __builtin_amdgcn_mfma_f32_16x16x32_bf16(a[1], b[0], acc[1][0], 0, 0, 0);
    acc[1][1] = __builtin_amdgcn_mfma_f32_16x16x32_bf16(a[1], b[1], acc[1][1], 0, 0, 0);
  }

#pragma unroll
  for (int mi = 0; mi < 2; ++mi)
#pragma unroll
    for (int ni = 0; ni < 2; ++ni)
#pragma unroll
      for (int r = 0; r < 4; ++r)
        Cs[w][mi * 16 + lhi * 4 + r][ni * 16 + llo] = acc[mi][ni][r];
  __syncthreads();
#pragma unroll
  for (int i = 0; i < 4; ++i) {
    int e = t + i * 256;              // 0..1023
    int kc = e >> 5, vc = e & 31;
    float sum = Cs[0][kc][vc] + Cs[1][kc][vc] + Cs[2][kc][vc] + Cs[3][kc][vc];
    ctxp[((size_t)hf * 128 + nh) * 1024 + e] = sum;
  }
}

// ---------------------------------------------------------------------------
// proj: M_n[o][h*32+kc] = sum_vc Wr[o][h*32+vc] * ctx[n,h][kc][vc], bf16
// ---------------------------------------------------------------------------
__global__ __launch_bounds__(256)
void proj_kernel(const float* __restrict__ ctxp, const float* __restrict__ Wr,
                 unsigned short* __restrict__ M)
{
  __shared__ float cs[32][33];
  const int nh = blockIdx.x;
  const int n = nh >> 3, h = nh & 7;
  const int t = threadIdx.x;
#pragma unroll
  for (int i = 0; i < 4; ++i) {
    int e = t + i * 256;
    cs[e >> 5][e & 31] = ctxp[(size_t)nh * 1024 + e] + ctxp[((size_t)128 + nh) * 1024 + e];
  }
  __syncthreads();
  float wreg[32];
  const float* wp = Wr + (size_t)t * 256 + h * 32;
#pragma unroll
  for (int i = 0; i < 8; ++i) {
    f32x4 v = *(const f32x4*)(wp + i * 4);
    wreg[i * 4] = v.x; wreg[i * 4 + 1] = v.y; wreg[i * 4 + 2] = v.z; wreg[i * 4 + 3] = v.w;
  }
  unsigned short o16[32];
#pragma unroll
  for (int kc = 0; kc < 32; ++kc) {
    float s = 0.f;
#pragma unroll
    for (int vv = 0; vv < 32; ++vv) s += wreg[vv] * cs[kc][vv];
    o16[kc] = f2b(s);
  }
  unsigned short* mp = M + (size_t)(n * CD + t) * 256 + h * 32;
#pragma unroll
  for (int i = 0; i < 8; ++i) {
    unsigned int lo = (unsigned int)o16[i * 4]     | ((unsigned int)o16[i * 4 + 1] << 16);
    unsigned int hi = (unsigned int)o16[i * 4 + 2] | ((unsigned int)o16[i * 4 + 3] << 16);
    *(uint2*)(mp + i * 4) = make_uint2(lo, hi);
  }
}

// ---------------------------------------------------------------------------
// out = M_n @ q_sm + br + x   (fp32 out, residual)
// ---------------------------------------------------------------------------
__global__ __launch_bounds__(256, 2)
void out_kernel(const unsigned short* __restrict__ M,
                const unsigned short* __restrict__ qsm,
                const float* __restrict__ br,
                const float* __restrict__ x,
                float* __restrict__ out)
{
  __shared__ __align__(16) unsigned short As[64 * 264];
  __shared__ __align__(16) unsigned short Bs[64 * 264];
  const int t = threadIdx.x;
  const int lt = blockIdx.x, mt = blockIdx.y, n = blockIdx.z;
  const int l0 = lt * 64, m0 = mt * 64;

  const unsigned short* Mn = M + (size_t)n * CD * 256;
#pragma unroll
  for (int i = 0; i < 8; ++i) {
    int idx = t + i * 256;            // 0..2047
    int row = idx >> 5, s8 = (idx & 31) << 3;
    *(short8*)(As + row * 264 + s8) = *(const short8*)(Mn + (size_t)(m0 + row) * 256 + s8);
  }
  const unsigned short* qn = qsm + (size_t)n * CD * HWD;
  {
    int l = t & 63, g0 = t >> 6;
#pragma unroll
    for (int i = 0; i < 16; ++i) {
      int c = (g0 + i * 4) << 2;
      unsigned short q0 = qn[(size_t)(c + 0) * HWD + l0 + l];
      unsigned short q1 = qn[(size_t)(c + 1) * HWD + l0 + l];
      unsigned short q2 = qn[(size_t)(c + 2) * HWD + l0 + l];
      unsigned short q3 = qn[(size_t)(c + 3) * HWD + l0 + l];
      unsigned int lo = (unsigned int)q0 | ((unsigned int)q1 << 16);
      unsigned int hi = (unsigned int)q2 | ((unsigned int)q3 << 16);
      *(uint2*)(Bs + l * 264 + c) = make_uint2(lo, hi);
    }
  }
  __syncthreads();

  const int w = t >> 6, lane = t & 63;
  const int wr = (w >> 1) * 32, wc = (w & 1) * 32;
  const int lhi = lane >> 4, llo = lane & 15;

  f32x4 acc[2][2] = {};
#pragma unroll
  for (int kk = 0; kk < 8; ++kk) {
    const int koff = kk * 32 + lhi * 8;
    short8 a0 = *(const short8*)(As + (wr + llo) * 264 + koff);
    short8 a1 = *(const short8*)(As + (wr + 16 + llo) * 264 + koff);
    short8 b0 = *(const short8*)(Bs + (wc + llo) * 264 + koff);
    short8 b1 = *(const short8*)(Bs + (wc + 16 + llo) * 264 + koff);
    acc[0][0] = __builtin_amdgcn_mfma_f32_16x16x32_bf16(a0, b0, acc[0][0], 0, 0, 0);
    acc[0][1] = __builtin_amdgcn_mfma_f32_16x16x32_bf16(a0, b1, acc[0][1], 0, 0, 0);
    acc[1][0] = __builtin_amdgcn_mfma_f32_16x16x32_bf16(a1, b0, acc[1][0], 0, 0, 0);
    acc[1][1] = __builtin_amdgcn_mfma_f32_16x16x32_bf16(a1, b1, acc[1][1], 0, 0, 0);
  }
  __syncthreads();

  float* Qs = (float*)As;             // 64 x 65
#pragma unroll
  for (int mi = 0; mi < 2; ++mi)
#pragma unroll
    for (int ni = 0; ni < 2; ++ni)
#pragma unroll
      for (int r = 0; r < 4; ++r) {
        int row = wr + mi * 16 + lhi * 4 + r;
        int col = wc + ni * 16 + llo;
        Qs[row * 65 + col] = acc[mi][ni][r] + br[m0 + row];
      }
  __syncthreads();

  const float* xn = x + (size_t)n * CD * HWD;
  {
    int l = t & 63, r0 = t >> 6;
#pragma unroll
    for (int i = 0; i < 16; ++i) {
      int row = r0 + i * 4;
      size_t off = (size_t)(m0 + row) * HWD + l0 + l;
      out[(size_t)n * CD * HWD + off] = Qs[row * 65 + l] + xn[off];
    }
  }
}

// ---------------------------------------------------------------------------
extern "C" void kernel_launch(void* const* d_in, const int* in_sizes, int n_in,
                              void* d_out, int out_size, void* d_ws, size_t ws_size,
                              hipStream_t stream) {
  const float* x  = (const float*)d_in[0];
  const float* Wk = (const float*)d_in[1];
  const float* bk = (const float*)d_in[2];
  const float* Wq = (const float*)d_in[3];
  const float* bq = (const float*)d_in[4];
  const float* Wv = (const float*)d_in[5];
  const float* bv = (const float*)d_in[6];
  const float* Wr = (const float*)d_in[7];
  const float* br = (const float*)d_in[8];
  float* out = (float*)d_out;

  char* ws = (char*)d_ws;
  // ws layout (bytes): keys 32M | vals 32M | qsm 32M | stats 32K | ctx 1M | M 2M | Wc 384K
  unsigned short* keys = (unsigned short*)(ws);
  unsigned short* vals = (unsigned short*)(ws + 33554432);
  unsigned short* qsm  = (unsigned short*)(ws + 67108864);
  float* stats         = (float*)(ws + 100663296);
  float* ctxp          = (float*)(ws + 100696064);
  unsigned short* M    = (unsigned short*)(ws + 101744640);
  unsigned short* Wc   = (unsigned short*)(ws + 103841792);
  // xT (bf16, 32MB) lives in d_out scratch: fully dead before out_kernel writes it.
  unsigned short* xT   = (unsigned short*)d_out;

  hipLaunchKernelGGL(prep_kernel, dim3(192), dim3(256), 0, stream, Wk, Wq, Wv, Wc);
  hipLaunchKernelGGL(xt_kernel, dim3(64, 4, NB), dim3(256), 0, stream, x, xT);
  hipLaunchKernelGGL(kqv_kernel, dim3(32, 6, NB), dim3(256), 0, stream,
                     Wc, xT, bk, bq, bv, keys, qsm, vals);
  hipLaunchKernelGGL(rowstats_kernel, dim3(NB * CD), dim3(256), 0, stream, keys, stats);
  hipLaunchKernelGGL(ctx_kernel, dim3(2, 128), dim3(256), 0, stream,
                     keys, vals, stats, ctxp);
  hipLaunchKernelGGL(proj_kernel, dim3(128), dim3(256), 0, stream, ctxp, Wr, M);
  hipLaunchKernelGGL(out_kernel, dim3(64, 4, NB), dim3(256), 0, stream,
                     M, qsm, br, x, out);
}